// Round 1
// baseline (398.036 us; speedup 1.0000x reference)
//
#include <hip/hip_runtime.h>

// SSIM loss, fused single pass.
// Layout: [N=32, C=3, H=512, W=512] fp32 -> 96 planes of 512x512.
// Separable 11-tap Gaussian: horizontal via LDS row windows, vertical via
// per-thread rotating pending accumulators (static indices via unroll-by-11).

#define IMG_H   512
#define IMG_W   512
#define BANDS   8
#define RB      64          // output rows per band (8*64 = 512)
#define NCHUNK  7           // 7*11 = 77 input rows processed (64+10 halo + 3 waste)
#define LDSW    528         // 512 + 5 left pad + 11 right pad
#define SSIM_C1 1e-4f
#define SSIM_C2 9e-4f

template<bool FIRST>
__device__ __forceinline__ float process11(const float (*lp)[LDSW], const float (*lt)[LDSW],
                                           const float g[11], float (&acc)[11][5],
                                           int chunk, int tid) {
    float lsum = 0.f;
    #pragma unroll
    for (int ph = 0; ph < 11; ++ph) {
        // ---- horizontal 11-tap conv of p, t, p^2, t^2, p*t at column tid ----
        float hp = 0.f, ht = 0.f, hpp = 0.f, htt = 0.f, hpt = 0.f;
        #pragma unroll
        for (int k = 0; k < 11; ++k) {
            const float w = g[k];
            const float a = lp[ph][tid + k];
            const float b = lt[ph][tid + k];
            hp = fmaf(w, a, hp);
            ht = fmaf(w, b, ht);
            const float wa = w * a;
            hpp = fmaf(wa, a, hpp);
            hpt = fmaf(wa, b, hpt);
            const float wb = w * b;
            htt = fmaf(wb, b, htt);
        }
        // ---- vertical: scatter this h-row into the 11 pending output rows ----
        // local input index i = chunk*11 + ph; contributes weight g[i-l] to
        // output row l in [i-10, i]; slot(l) = l mod 11.
        #pragma unroll
        for (int s = 0; s < 11; ++s) {
            const int m = (s - ph + 21) % 11;       // l = i-10+m, static per (ph,s)
            if (FIRST && (ph - 10 + m) < 0) continue; // chunk 0: skip l < 0
            const float w = g[10 - m];
            acc[s][0] = fmaf(w, hp,  acc[s][0]);
            acc[s][1] = fmaf(w, ht,  acc[s][1]);
            acc[s][2] = fmaf(w, hpp, acc[s][2]);
            acc[s][3] = fmaf(w, htt, acc[s][3]);
            acc[s][4] = fmaf(w, hpt, acc[s][4]);
        }
        // ---- emit completed output row l = i-10 (slot (ph+1)%11), then reset ----
        if (!FIRST || ph == 10) {
            const int l  = chunk * 11 + ph - 10;
            const int se = (ph + 1) % 11;           // static after unroll
            if (l < RB) {
                const float mp = acc[se][0], mt = acc[se][1];
                const float mpp = mp * mp, mtt = mt * mt, mpt = mp * mt;
                const float sp  = acc[se][2] - mpp;
                const float st  = acc[se][3] - mtt;
                const float spt = acc[se][4] - mpt;
                const float num = (2.f * mpt + SSIM_C1) * (2.f * spt + SSIM_C2);
                const float den = (mpp + mtt + SSIM_C1) * (sp + st + SSIM_C2);
                lsum += num * __builtin_amdgcn_rcpf(den);  // den >= C1*C2 > 0
            }
            #pragma unroll
            for (int q = 0; q < 5; ++q) acc[se][q] = 0.f;
        }
    }
    return lsum;
}

__global__ __launch_bounds__(512) void ssim_main(const float* __restrict__ pred,
                                                 const float* __restrict__ targ,
                                                 float* __restrict__ out) {
    __shared__ float lp[11][LDSW];
    __shared__ float lt[11][LDSW];
    __shared__ float wsum[8];

    const int tid   = threadIdx.x;            // owns column x = tid
    const int band  = blockIdx.x;             // 0..7
    const int plane = blockIdx.y;             // 0..95
    const size_t base = (size_t)plane * (IMG_H * IMG_W);
    const int r0 = band * RB - 5;             // first (halo) input row

    // Gaussian taps, computed per-thread (sigma = 1.5)
    float g[11];
    {
        float s = 0.f;
        #pragma unroll
        for (int d = 0; d < 11; ++d) {
            const float x = (float)(d - 5);
            g[d] = __expf(x * x * (-1.f / 4.5f));
            s += g[d];
        }
        const float inv = 1.f / s;
        #pragma unroll
        for (int d = 0; d < 11; ++d) g[d] *= inv;
    }

    // Zero LDS once: interior gets overwritten every chunk, pads stay zero.
    {
        float* z0 = &lp[0][0];
        float* z1 = &lt[0][0];
        for (int idx = tid; idx < 11 * LDSW; idx += 512) { z0[idx] = 0.f; z1[idx] = 0.f; }
    }

    float acc[11][5];
    #pragma unroll
    for (int s = 0; s < 11; ++s)
        #pragma unroll
        for (int q = 0; q < 5; ++q) acc[s][q] = 0.f;

    float lsum = 0.f;

    for (int chunk = 0; chunk < NCHUNK; ++chunk) {
        __syncthreads();                       // WAR: prev chunk's reads done (also covers zero-init)
        #pragma unroll
        for (int ph = 0; ph < 11; ++ph) {
            const int r = r0 + chunk * 11 + ph;
            float vp = 0.f, vt = 0.f;
            if (r >= 0 && r < IMG_H) {
                const size_t o = base + (size_t)r * IMG_W + tid;
                vp = pred[o];
                vt = targ[o];
            }
            lp[ph][5 + tid] = vp;
            lt[ph][5 + tid] = vt;
        }
        __syncthreads();                       // writes visible
        if (chunk == 0)
            lsum += process11<true >(lp, lt, g, acc, chunk, tid);
        else
            lsum += process11<false>(lp, lt, g, acc, chunk, tid);
    }

    // block reduction: wave shuffle -> LDS -> one atomic per block
    #pragma unroll
    for (int off = 32; off > 0; off >>= 1) lsum += __shfl_down(lsum, off);
    const int lane = tid & 63, wid = tid >> 6;
    if (lane == 0) wsum[wid] = lsum;
    __syncthreads();
    if (tid == 0) {
        float s = 0.f;
        #pragma unroll
        for (int w = 0; w < 8; ++w) s += wsum[w];
        atomicAdd(out, s);
    }
}

__global__ void ssim_finalize(float* out) {
    out[0] = 1.0f - out[0] * (1.0f / 25165824.0f);  // 1 - sum/(32*3*512*512)
}

extern "C" void kernel_launch(void* const* d_in, const int* in_sizes, int n_in,
                              void* d_out, int out_size, void* d_ws, size_t ws_size,
                              hipStream_t stream) {
    (void)in_sizes; (void)n_in; (void)out_size; (void)d_ws; (void)ws_size;
    const float* pred = (const float*)d_in[0];
    const float* targ = (const float*)d_in[1];
    float* out = (float*)d_out;

    hipMemsetAsync(out, 0, sizeof(float), stream);
    ssim_main<<<dim3(BANDS, 96), 512, 0, stream>>>(pred, targ, out);
    ssim_finalize<<<1, 1, 0, stream>>>(out);
}

// Round 2
// 389.908 us; speedup vs baseline: 1.0208x; 1.0208x over previous
//
#include <hip/hip_runtime.h>

// SSIM loss, fused single pass, barrier-free.
// [32,3,512,512] fp32 = 96 planes of 512x512.
// Each WAVE owns a 64x64 output tile: 64 lanes = 64 columns. Horizontal
// 11-tap conv from a per-wave-private LDS row strip (64+10 halo cols,
// 2-row double buffer); vertical 11-tap via rotating pending accumulators
// with static indices (unroll-by-11). No __syncthreads in the hot loop:
// LDS is wave-private, ordering is wave-synchronous (lgkmcnt).

#define IMG_H   512
#define IMG_W   512
#define TH      64          // tile rows per wave
#define TW      64          // tile cols per wave (= lanes)
#define NCHUNK  7           // 7*11 = 77 row-phases (74 input rows needed)
#define LROW    80          // LDS row stride: 74 used, padded
#define SSIM_C1 1e-4f
#define SSIM_C2 9e-4f

__global__ __launch_bounds__(256, 4) void ssim_main(const float* __restrict__ pred,
                                                    const float* __restrict__ targ,
                                                    float* __restrict__ out) {
    __shared__ float lds[4][2][2][LROW];   // [wave][buf][arr p/t][col] = 5.1 KB
    __shared__ float wsum[4];

    const int tid  = threadIdx.x;
    const int lane = tid & 63;
    const int wid  = tid >> 6;

    // 6144 tiles = 8 col-strips x 8 row-bands x 96 planes; 4 waves/block.
    // Col-strip fastest: the 4 waves of a block share rows -> halo L2 hits.
    const int gtile = blockIdx.x * 4 + wid;
    const int colt  = gtile & 7;
    const int rowt  = (gtile >> 3) & 7;
    const int plane = gtile >> 6;
    const size_t base = (size_t)plane * (IMG_H * IMG_W);
    const int c0 = colt * TW;
    const int r0 = rowt * TH;

    float (*B)[2][LROW] = lds[wid];

    // Gaussian taps (sigma = 1.5), per-thread
    float g[11];
    {
        float s = 0.f;
        #pragma unroll
        for (int d = 0; d < 11; ++d) {
            const float x = (float)(d - 5);
            g[d] = __expf(x * x * (-1.f / 4.5f));
            s += g[d];
        }
        const float inv = 1.f / s;
        #pragma unroll
        for (int d = 0; d < 11; ++d) g[d] *= inv;
    }

    const int  cm   = c0 - 5 + lane;              // main load column
    const int  ch   = c0 + 59 + lane;             // halo load column (lane<10)
    const bool cmok = (cm >= 0) && (cm < IMG_W);
    const bool chok = (lane < 10) && (ch < IMG_W);

    // Preload input row j=0 (global row r0-5) into buffer 0.
    {
        const int  rg  = r0 - 5;
        const bool rok = (rg >= 0);               // rg < IMG_H always here
        const size_t ro = base + (size_t)rg * IMG_W;
        float vp0 = 0.f, vt0 = 0.f, vp1 = 0.f, vt1 = 0.f;
        if (rok && cmok) { vp0 = pred[ro + cm]; vt0 = targ[ro + cm]; }
        if (rok && chok) { vp1 = pred[ro + ch]; vt1 = targ[ro + ch]; }
        B[0][0][lane] = vp0;
        B[0][1][lane] = vt0;
        if (lane < 10) { B[0][0][64 + lane] = vp1; B[0][1][64 + lane] = vt1; }
    }

    float acc[11][5];
    #pragma unroll
    for (int s = 0; s < 11; ++s)
        #pragma unroll
        for (int q = 0; q < 5; ++q) acc[s][q] = 0.f;

    float lsum = 0.f;

    for (int chunk = 0; chunk < NCHUNK; ++chunk) {
        const int parity = chunk & 1;
        #pragma unroll
        for (int ph = 0; ph < 11; ++ph) {
            const int j = chunk * 11 + ph;        // current row-phase

            // ---- prefetch input row j+1 into registers ----
            const int  rg  = r0 - 5 + j + 1;
            const bool rok = (rg >= 0) && (rg < IMG_H);
            const size_t ro = base + (size_t)rg * IMG_W;
            float vp0 = 0.f, vt0 = 0.f, vp1 = 0.f, vt1 = 0.f;
            if (rok && cmok) { vp0 = pred[ro + cm]; vt0 = targ[ro + cm]; }
            if (rok && chok) { vp1 = pred[ro + ch]; vt1 = targ[ro + ch]; }

            // ---- horizontal 11-tap conv of p,t,p^2,t^2,pt at col c0+lane ----
            const int rb = parity ^ (ph & 1);     // read buffer for row j
            const float* Lp = B[rb][0];
            const float* Lt = B[rb][1];
            float hp = 0.f, ht = 0.f, hpp = 0.f, htt = 0.f, hpt = 0.f;
            #pragma unroll
            for (int k = 0; k < 11; ++k) {
                const float w = g[k];
                const float a = Lp[lane + k];
                const float b = Lt[lane + k];
                hp  = fmaf(w, a, hp);
                ht  = fmaf(w, b, ht);
                const float wa = w * a;
                hpp = fmaf(wa, a, hpp);
                hpt = fmaf(wa, b, hpt);
                const float wb = w * b;
                htt = fmaf(wb, b, htt);
            }

            // ---- vertical scatter: row j feeds outputs l = j-10 .. j ----
            // slot(l) = l % 11 = (ph+1+m) % 11; weight g[j-l] = g[10-m].
            // l<0 slots accumulate dead values; they're reset before reuse.
            #pragma unroll
            for (int s = 0; s < 11; ++s) {
                const int m = (s - ph + 21) % 11;
                const float w = g[10 - m];
                acc[s][0] = fmaf(w, hp,  acc[s][0]);
                acc[s][1] = fmaf(w, ht,  acc[s][1]);
                acc[s][2] = fmaf(w, hpp, acc[s][2]);
                acc[s][3] = fmaf(w, htt, acc[s][3]);
                acc[s][4] = fmaf(w, hpt, acc[s][4]);
            }

            // ---- emit completed output row l = j-10 (slot (ph+1)%11) ----
            const int l  = j - 10;
            const int se = (ph + 1) % 11;         // static after unroll
            if (l >= 0 && l < TH) {
                const float mp = acc[se][0], mt = acc[se][1];
                const float mpp = mp * mp, mtt = mt * mt, mpt = mp * mt;
                const float sp  = acc[se][2] - mpp;
                const float st  = acc[se][3] - mtt;
                const float spt = acc[se][4] - mpt;
                const float num = (2.f * mpt + SSIM_C1) * (2.f * spt + SSIM_C2);
                const float den = (mpp + mtt + SSIM_C1) * (sp + st + SSIM_C2);
                lsum += num * __builtin_amdgcn_rcpf(den);  // den >= C1*C2 > 0
            }
            #pragma unroll
            for (int q = 0; q < 5; ++q) acc[se][q] = 0.f;

            // ---- store prefetched row j+1 into the other buffer ----
            float (*W)[LROW] = B[rb ^ 1];
            W[0][lane] = vp0;
            W[1][lane] = vt0;
            if (lane < 10) { W[0][64 + lane] = vp1; W[1][64 + lane] = vt1; }
        }
    }

    // wave reduce -> one atomic per block (only sync in the kernel)
    #pragma unroll
    for (int off = 32; off > 0; off >>= 1) lsum += __shfl_down(lsum, off);
    if (lane == 0) wsum[wid] = lsum;
    __syncthreads();
    if (tid == 0) atomicAdd(out, wsum[0] + wsum[1] + wsum[2] + wsum[3]);
}

__global__ void ssim_finalize(float* out) {
    out[0] = 1.0f - out[0] * (1.0f / 25165824.0f);  // 1 - sum/(32*3*512*512)
}

extern "C" void kernel_launch(void* const* d_in, const int* in_sizes, int n_in,
                              void* d_out, int out_size, void* d_ws, size_t ws_size,
                              hipStream_t stream) {
    (void)in_sizes; (void)n_in; (void)out_size; (void)d_ws; (void)ws_size;
    const float* pred = (const float*)d_in[0];
    const float* targ = (const float*)d_in[1];
    float* out = (float*)d_out;

    hipMemsetAsync(out, 0, sizeof(float), stream);
    ssim_main<<<dim3(1536), 256, 0, stream>>>(pred, targ, out);
    ssim_finalize<<<1, 1, 0, stream>>>(out);
}

// Round 3
// 287.651 us; speedup vs baseline: 1.3837x; 1.3555x over previous
//
#include <hip/hip_runtime.h>

// SSIM loss, fused single pass, barrier-free, spill-free.
// [32,3,512,512] fp32 = 96 planes of 512x512. Each WAVE owns a 64x64 tile.
// Horizontal 11-tap from a wave-private LDS float2 row strip (double-buffered);
// vertical 11-tap via a mod-11 ring of 55 accumulators. All ring indices are
// compile-time literals via template<int PH> phase instantiation + macro
// scatter, so acc[] is guaranteed register-resident (round-2 failure mode:
// partial unroll -> dynamic indices -> scratch spill, 97 MB HBM writes).

#define IMG_H   512
#define IMG_W   512
#define TH      64          // tile rows per wave
#define NCHUNK  7           // 7*11 = 77 row-phases (74 input rows needed)
#define LROW    80          // LDS row stride in float2 (74 used)
#define SSIM_C1 1e-4f
#define SSIM_C2 9e-4f

// Gaussian taps, sigma=1.5, window 11 (precomputed in double, symmetric).
__device__ constexpr float G[11] = {
    0.00102838f, 0.00759879f, 0.03600078f, 0.10936070f, 0.21300563f,
    0.26601180f,
    0.21300563f, 0.10936070f, 0.03600078f, 0.00759879f, 0.00102838f
};

template<int PH>
__device__ __forceinline__ void phase(const float* __restrict__ pred,
                                      const float* __restrict__ targ,
                                      size_t base, int r0, int j, int rb,
                                      float2 (*B)[LROW],
                                      int lane, int cm, int ch,
                                      bool cmok, bool chok,
                                      float (&acc)[11][5], float& lsum) {
    // ---- prefetch input row j+1 into registers ----
    const int  rg  = r0 - 5 + j + 1;
    const bool rok = (rg >= 0) && (rg < IMG_H);
    const size_t ro = base + (size_t)rg * IMG_W;
    float vp0 = 0.f, vt0 = 0.f, vp1 = 0.f, vt1 = 0.f;
    if (rok && cmok) { vp0 = pred[ro + cm]; vt0 = targ[ro + cm]; }
    if (rok && chok) { vp1 = pred[ro + ch]; vt1 = targ[ro + ch]; }

    // ---- horizontal 11-tap conv of p,t,p^2,t^2,pt at this lane's column ----
    const float2* L = B[rb];
    float hp = 0.f, ht = 0.f, hpp = 0.f, htt = 0.f, hpt = 0.f;
    #pragma unroll
    for (int k = 0; k < 11; ++k) {
        const float  w = G[k];
        const float2 v = L[lane + k];
        hp  = fmaf(w, v.x, hp);
        ht  = fmaf(w, v.y, ht);
        const float wa = w * v.x;
        hpp = fmaf(wa, v.x, hpp);
        hpt = fmaf(wa, v.y, hpt);
        const float wb = w * v.y;
        htt = fmaf(wb, v.y, htt);
    }

    // ---- vertical scatter: H[j] feeds outputs l = j-10..j, slot = l%11 ----
    // All indices literal: acc stays in VGPRs.
#define SCAT(s) { constexpr int m = ((s) - PH + 21) % 11;                    \
                  constexpr float w = G[10 - m];                             \
                  acc[s][0] = fmaf(w, hp,  acc[s][0]);                       \
                  acc[s][1] = fmaf(w, ht,  acc[s][1]);                       \
                  acc[s][2] = fmaf(w, hpp, acc[s][2]);                       \
                  acc[s][3] = fmaf(w, htt, acc[s][3]);                       \
                  acc[s][4] = fmaf(w, hpt, acc[s][4]); }
    SCAT(0) SCAT(1) SCAT(2) SCAT(3) SCAT(4) SCAT(5)
    SCAT(6) SCAT(7) SCAT(8) SCAT(9) SCAT(10)
#undef SCAT

    // ---- emit completed output row l = j-10 (slot (PH+1)%11), then reset ----
    constexpr int SE = (PH + 1) % 11;
    const int l = j - 10;
    if (l >= 0 && l < TH) {                       // wave-uniform branch
        const float mp = acc[SE][0], mt = acc[SE][1];
        const float mpp = mp * mp, mtt = mt * mt, mpt = mp * mt;
        const float sp  = acc[SE][2] - mpp;
        const float st  = acc[SE][3] - mtt;
        const float spt = acc[SE][4] - mpt;
        const float num = (2.f * mpt + SSIM_C1) * (2.f * spt + SSIM_C2);
        const float den = (mpp + mtt + SSIM_C1) * (sp + st + SSIM_C2);
        lsum += num * __builtin_amdgcn_rcpf(den); // den >= C1*C2 > 0
    }
    acc[SE][0] = 0.f; acc[SE][1] = 0.f; acc[SE][2] = 0.f;
    acc[SE][3] = 0.f; acc[SE][4] = 0.f;

    // ---- store prefetched row j+1 into the other buffer ----
    float2* W = B[rb ^ 1];
    W[lane] = make_float2(vp0, vt0);
    if (lane < 10) W[64 + lane] = make_float2(vp1, vt1);
}

__global__ __launch_bounds__(256, 4) void ssim_main(const float* __restrict__ pred,
                                                    const float* __restrict__ targ,
                                                    float* __restrict__ out) {
    __shared__ float2 lds[4][2][LROW];   // [wave][buf][col] {p,t} = 5.1 KB
    __shared__ float  wsum[4];

    const int tid  = threadIdx.x;
    const int lane = tid & 63;
    const int wid  = tid >> 6;

    // 6144 tiles = 8 col-strips x 8 row-bands x 96 planes; 4 waves/block.
    const int gtile = blockIdx.x * 4 + wid;
    const int colt  = gtile & 7;
    const int rowt  = (gtile >> 3) & 7;
    const int plane = gtile >> 6;
    const size_t base = (size_t)plane * (IMG_H * IMG_W);
    const int c0 = colt * TH;
    const int r0 = rowt * TH;

    float2 (*B)[LROW] = lds[wid];

    const int  cm   = c0 - 5 + lane;              // main load column
    const int  ch   = c0 + 59 + lane;             // halo load column (lane<10)
    const bool cmok = (cm >= 0) && (cm < IMG_W);
    const bool chok = (lane < 10) && (ch < IMG_W);

    // Preload input row j=0 (global row r0-5) into buffer 0.
    {
        const int  rg  = r0 - 5;
        const bool rok = (rg >= 0);
        const size_t ro = base + (size_t)rg * IMG_W;
        float vp0 = 0.f, vt0 = 0.f, vp1 = 0.f, vt1 = 0.f;
        if (rok && cmok) { vp0 = pred[ro + cm]; vt0 = targ[ro + cm]; }
        if (rok && chok) { vp1 = pred[ro + ch]; vt1 = targ[ro + ch]; }
        B[0][lane] = make_float2(vp0, vt0);
        if (lane < 10) B[0][64 + lane] = make_float2(vp1, vt1);
    }

    float acc[11][5];
    #pragma unroll
    for (int s = 0; s < 11; ++s) {
        acc[s][0] = 0.f; acc[s][1] = 0.f; acc[s][2] = 0.f;
        acc[s][3] = 0.f; acc[s][4] = 0.f;
    }

    float lsum = 0.f;

    for (int chunk = 0; chunk < NCHUNK; ++chunk) {
        const int parity = chunk & 1;
        const int j0 = chunk * 11;
#define P(n) phase<n>(pred, targ, base, r0, j0 + n, parity ^ ((n) & 1), B, \
                      lane, cm, ch, cmok, chok, acc, lsum);
        P(0) P(1) P(2) P(3) P(4) P(5) P(6) P(7) P(8) P(9) P(10)
#undef P
    }

    // wave reduce -> one atomic per block
    #pragma unroll
    for (int off = 32; off > 0; off >>= 1) lsum += __shfl_down(lsum, off);
    if (lane == 0) wsum[wid] = lsum;
    __syncthreads();
    if (tid == 0) atomicAdd(out, wsum[0] + wsum[1] + wsum[2] + wsum[3]);
}

__global__ void ssim_finalize(float* out) {
    out[0] = 1.0f - out[0] * (1.0f / 25165824.0f);  // 1 - sum/(32*3*512*512)
}

extern "C" void kernel_launch(void* const* d_in, const int* in_sizes, int n_in,
                              void* d_out, int out_size, void* d_ws, size_t ws_size,
                              hipStream_t stream) {
    (void)in_sizes; (void)n_in; (void)out_size; (void)d_ws; (void)ws_size;
    const float* pred = (const float*)d_in[0];
    const float* targ = (const float*)d_in[1];
    float* out = (float*)d_out;

    hipMemsetAsync(out, 0, sizeof(float), stream);
    ssim_main<<<dim3(1536), 256, 0, stream>>>(pred, targ, out);
    ssim_finalize<<<1, 1, 0, stream>>>(out);
}

// Round 5
// 285.870 us; speedup vs baseline: 1.3924x; 1.0062x over previous
//
#include <hip/hip_runtime.h>

// SSIM loss, fused single pass, barrier-free, spill-free.
// [32,3,512,512] fp32 = 96 planes of 512x512. Each WAVE owns a 64x64 tile.
// Round-5: EXACT round-3 arithmetic (verified, absmax 3.9e-3) +
//  - readfirstlane-scalarized tile coords -> SALU row addressing
//  - block partial sums to d_ws + reduce kernel (no memset, no atomics)
// Round-4's bundled changes (s/d algebra, FP-masked loads, mask-emit,
// launch_bounds(256,6)) caused a genuine ~0.035 loss error; reverted for
// isolation.

#define IMG_H   512
#define IMG_W   512
#define TH      64          // tile rows/cols per wave
#define NCHUNK  7           // 7*11 = 77 row-phases (74 input rows needed)
#define LROW    80          // LDS row stride in float2 (74 used)
#define SSIM_C1 1e-4f
#define SSIM_C2 9e-4f

// Gaussian taps, sigma=1.5, window 11.
__device__ constexpr float G[11] = {
    0.00102838f, 0.00759879f, 0.03600078f, 0.10936070f, 0.21300563f,
    0.26601180f,
    0.21300563f, 0.10936070f, 0.03600078f, 0.00759879f, 0.00102838f
};

template<int PH>
__device__ __forceinline__ void phase(const float* __restrict__ ppl,
                                      const float* __restrict__ tpl,
                                      int r0, int j, int rb,
                                      float2 (*B)[LROW],
                                      int lane, int cm, int ch,
                                      bool cmok, bool chok,
                                      float (&acc)[11][5], float& lsum) {
    // ---- prefetch input row j+1 into registers (rg is SCALAR: r0,j uniform) ----
    const int  rg  = r0 - 5 + j + 1;
    const bool rok = (rg >= 0) && (rg < IMG_H);
    const size_t ro = (size_t)rg * IMG_W;
    float vp0 = 0.f, vt0 = 0.f, vp1 = 0.f, vt1 = 0.f;
    if (rok && cmok) { vp0 = ppl[ro + cm]; vt0 = tpl[ro + cm]; }
    if (rok && chok) { vp1 = ppl[ro + ch]; vt1 = tpl[ro + ch]; }

    // ---- horizontal 11-tap conv of p,t,p^2,t^2,pt at this lane's column ----
    const float2* L = B[rb];
    float hp = 0.f, ht = 0.f, hpp = 0.f, htt = 0.f, hpt = 0.f;
    #pragma unroll
    for (int k = 0; k < 11; ++k) {
        const float  w = G[k];
        const float2 v = L[lane + k];
        hp  = fmaf(w, v.x, hp);
        ht  = fmaf(w, v.y, ht);
        const float wa = w * v.x;
        hpp = fmaf(wa, v.x, hpp);
        hpt = fmaf(wa, v.y, hpt);
        const float wb = w * v.y;
        htt = fmaf(wb, v.y, htt);
    }

    // ---- vertical scatter: row j feeds outputs l = j-10..j, slot = l%11 ----
#define SCAT(s) { constexpr int m = ((s) - PH + 21) % 11;                    \
                  constexpr float w = G[10 - m];                             \
                  acc[s][0] = fmaf(w, hp,  acc[s][0]);                       \
                  acc[s][1] = fmaf(w, ht,  acc[s][1]);                       \
                  acc[s][2] = fmaf(w, hpp, acc[s][2]);                       \
                  acc[s][3] = fmaf(w, htt, acc[s][3]);                       \
                  acc[s][4] = fmaf(w, hpt, acc[s][4]); }
    SCAT(0) SCAT(1) SCAT(2) SCAT(3) SCAT(4) SCAT(5)
    SCAT(6) SCAT(7) SCAT(8) SCAT(9) SCAT(10)
#undef SCAT

    // ---- emit completed output row l = j-10 (slot (PH+1)%11), then reset ----
    constexpr int SE = (PH + 1) % 11;
    const int l = j - 10;
    if (l >= 0 && l < TH) {                       // wave-uniform branch
        const float mp = acc[SE][0], mt = acc[SE][1];
        const float mpp = mp * mp, mtt = mt * mt, mpt = mp * mt;
        const float sp  = acc[SE][2] - mpp;
        const float st  = acc[SE][3] - mtt;
        const float spt = acc[SE][4] - mpt;
        const float num = (2.f * mpt + SSIM_C1) * (2.f * spt + SSIM_C2);
        const float den = (mpp + mtt + SSIM_C1) * (sp + st + SSIM_C2);
        lsum += num * __builtin_amdgcn_rcpf(den); // den >= C1*C2 > 0
    }
    acc[SE][0] = 0.f; acc[SE][1] = 0.f; acc[SE][2] = 0.f;
    acc[SE][3] = 0.f; acc[SE][4] = 0.f;

    // ---- store prefetched row j+1 into the other buffer ----
    float2* W = B[rb ^ 1];
    W[lane] = make_float2(vp0, vt0);
    if (lane < 10) W[64 + lane] = make_float2(vp1, vt1);
}

__global__ __launch_bounds__(256, 4) void ssim_main(const float* __restrict__ pred,
                                                    const float* __restrict__ targ,
                                                    float* __restrict__ ws) {
    __shared__ float2 lds[4][2][LROW];   // [wave][buf][col] {p,t} = 5.1 KB
    __shared__ float  wsum[4];

    const int tid  = threadIdx.x;
    const int lane = tid & 63;
    const int wid  = tid >> 6;

    // 6144 tiles = 8 col-strips x 8 row-bands x 96 planes; 4 waves/block.
    // readfirstlane -> tile coords in SGPRs -> scalar row addressing.
    const int gt    = __builtin_amdgcn_readfirstlane(blockIdx.x * 4 + wid);
    const int c0    = (gt & 7) * TH;
    const int r0    = ((gt >> 3) & 7) * TH;
    const int plane = gt >> 6;
    const float* ppl = pred + (size_t)plane * (IMG_H * IMG_W);
    const float* tpl = targ + (size_t)plane * (IMG_H * IMG_W);

    float2 (*B)[LROW] = lds[wid];

    const int  cm   = c0 - 5 + lane;              // main load column
    const int  ch   = c0 + 59 + lane;             // halo load column (lane<10)
    const bool cmok = (cm >= 0) && (cm < IMG_W);
    const bool chok = (lane < 10) && (ch < IMG_W);

    // Preload input row j=0 (global row r0-5) into buffer 0.
    {
        const int  rg  = r0 - 5;
        const bool rok = (rg >= 0);
        const size_t ro = (size_t)rg * IMG_W;
        float vp0 = 0.f, vt0 = 0.f, vp1 = 0.f, vt1 = 0.f;
        if (rok && cmok) { vp0 = ppl[ro + cm]; vt0 = tpl[ro + cm]; }
        if (rok && chok) { vp1 = ppl[ro + ch]; vt1 = tpl[ro + ch]; }
        B[0][lane] = make_float2(vp0, vt0);
        if (lane < 10) B[0][64 + lane] = make_float2(vp1, vt1);
    }

    float acc[11][5];
    #pragma unroll
    for (int s = 0; s < 11; ++s) {
        acc[s][0] = 0.f; acc[s][1] = 0.f; acc[s][2] = 0.f;
        acc[s][3] = 0.f; acc[s][4] = 0.f;
    }

    float lsum = 0.f;

    for (int chunk = 0; chunk < NCHUNK; ++chunk) {
        const int parity = chunk & 1;
        const int j0 = chunk * 11;
#define P(n) phase<n>(ppl, tpl, r0, j0 + n, parity ^ ((n) & 1), B, \
                      lane, cm, ch, cmok, chok, acc, lsum);
        P(0) P(1) P(2) P(3) P(4) P(5) P(6) P(7) P(8) P(9) P(10)
#undef P
    }

    // wave reduce -> one plain store per block into the workspace
    #pragma unroll
    for (int off = 32; off > 0; off >>= 1) lsum += __shfl_down(lsum, off);
    if (lane == 0) wsum[wid] = lsum;
    __syncthreads();
    if (tid == 0) ws[blockIdx.x] = wsum[0] + wsum[1] + wsum[2] + wsum[3];
}

__global__ __launch_bounds__(256) void ssim_finalize(const float* __restrict__ ws,
                                                     float* __restrict__ out) {
    __shared__ float wsum[4];
    const int tid  = threadIdx.x;
    const int lane = tid & 63;
    const int wid  = tid >> 6;
    float s = 0.f;
    #pragma unroll
    for (int i = 0; i < 6; ++i) s += ws[tid + 256 * i];   // 1536 = 6*256
    #pragma unroll
    for (int off = 32; off > 0; off >>= 1) s += __shfl_down(s, off);
    if (lane == 0) wsum[wid] = s;
    __syncthreads();
    if (tid == 0) {
        const float tot = wsum[0] + wsum[1] + wsum[2] + wsum[3];
        out[0] = 1.0f - tot * (1.0f / 25165824.0f);  // 1 - sum/(32*3*512*512)
    }
}

extern "C" void kernel_launch(void* const* d_in, const int* in_sizes, int n_in,
                              void* d_out, int out_size, void* d_ws, size_t ws_size,
                              hipStream_t stream) {
    (void)in_sizes; (void)n_in; (void)out_size; (void)ws_size;
    const float* pred = (const float*)d_in[0];
    const float* targ = (const float*)d_in[1];
    float* ws  = (float*)d_ws;          // 1536 floats of scratch
    float* out = (float*)d_out;

    ssim_main<<<dim3(1536), 256, 0, stream>>>(pred, targ, ws);
    ssim_finalize<<<1, 256, 0, stream>>>(ws, out);
}